// Round 4
// baseline (1023.530 us; speedup 1.0000x reference)
//
#include <hip/hip_runtime.h>
#include <math.h>
#include <stdint.h>

#define B_N 32768
#define V_N 2048
#define H_N 256
#define E_N 16
#define Q_N 4

// RNG variant: 1 = jax_threefry_partitionable (modern default), 0 = original rollout
// Round 4: double-tanh bug fixed; variant A/B restarts unconfounded. PART=1 first.
#define RNG_PART 1

// ---------------- Threefry2x32 (JAX-exact, 20 rounds; KAT-verified on HW r2) ----------------
#define TF_R(x0,x1,r) { x0 += x1; x1 = ((x1 << (r)) | (x1 >> (32-(r)))); x1 ^= x0; }

__device__ __forceinline__ void tf_block(uint32_t k0, uint32_t k1, uint32_t &x0, uint32_t &x1){
  uint32_t k2 = k0 ^ k1 ^ 0x1BD11BDAu;
  x0 += k0; x1 += k1;
  TF_R(x0,x1,13) TF_R(x0,x1,15) TF_R(x0,x1,26) TF_R(x0,x1,6)
  x0 += k1; x1 += k2 + 1u;
  TF_R(x0,x1,17) TF_R(x0,x1,29) TF_R(x0,x1,16) TF_R(x0,x1,24)
  x0 += k2; x1 += k0 + 2u;
  TF_R(x0,x1,13) TF_R(x0,x1,15) TF_R(x0,x1,26) TF_R(x0,x1,6)
  x0 += k0; x1 += k1 + 3u;
  TF_R(x0,x1,17) TF_R(x0,x1,29) TF_R(x0,x1,16) TF_R(x0,x1,24)
  x0 += k1; x1 += k2 + 4u;
  TF_R(x0,x1,13) TF_R(x0,x1,15) TF_R(x0,x1,26) TF_R(x0,x1,6)
  x0 += k2; x1 += k0 + 5u;
}

__device__ __forceinline__ int run_kats(){
  uint32_t x0, x1;
  x0 = 0u; x1 = 0u;
  tf_block(0u, 0u, x0, x1);
  if (x0 != 0x6b200159u || x1 != 0x99ba4efeu) return 1;
  x0 = 0xFFFFFFFFu; x1 = 0xFFFFFFFFu;
  tf_block(0xFFFFFFFFu, 0xFFFFFFFFu, x0, x1);
  if (x0 != 0x1cb996fcu || x1 != 0xbb002be7u) return 2;
  x0 = 0x243f6a88u; x1 = 0x85a308d3u;
  tf_block(0x13198a2eu, 0x03707344u, x0, x1);
  if (x0 != 0xc4923a9cu || x1 != 0x483df7a0u) return 3;
  return 0;
}

// random_bits(key, 32, (32768,))[b]
__device__ __forceinline__ uint32_t rbits(uint32_t ka, uint32_t kb, uint32_t b){
#if RNG_PART
  uint32_t x0 = 0u, x1 = b;
  tf_block(ka, kb, x0, x1);
  return x0 ^ x1;
#else
  uint32_t i = b & 16383u;
  uint32_t x0 = i, x1 = i + 16384u;
  tf_block(ka, kb, x0, x1);
  return (b < 16384u) ? x0 : x1;
#endif
}

// ---------------- S0: per-step keys + temperature schedule + KAT flag ----------------
__global__ void s0_kernel(unsigned* __restrict__ wsu, float log_ratio){
#pragma clang fp contract(off)
  int t = threadIdx.x;
  uint32_t ka = 0u, kb = 1u;  // jax.random.key(1) == (0,1)
  uint32_t kinit0, kinit1, kl0, kl1;
#if RNG_PART
  { uint32_t a0=0u,a1=0u; tf_block(ka,kb,a0,a1); kinit0=a0; kinit1=a1; }
  { uint32_t a0=0u,a1=1u; tf_block(ka,kb,a0,a1); kl0=a0; kl1=a1; }
#else
  { uint32_t c00=0u,c01=2u; tf_block(ka,kb,c00,c01);
    uint32_t c10=1u,c11=3u; tf_block(ka,kb,c10,c11);
    kinit0=c00; kinit1=c10; kl0=c01; kl1=c11; }
#endif
  if (t == 0){
    wsu[502] = (unsigned)run_kats();
    // randint lower-bits key for initial state = split(kinit)[1]
#if RNG_PART
    uint32_t x0=0u, x1=1u; tf_block(kinit0,kinit1,x0,x1);
    wsu[500]=x0; wsu[501]=x1;
#else
    uint32_t e00=0u,e01=2u; tf_block(kinit0,kinit1,e00,e01);
    uint32_t e10=1u,e11=3u; tf_block(kinit0,kinit1,e10,e11);
    wsu[500]=e01; wsu[501]=e11;
#endif
  }
  if (t < 100){
    uint32_t kt0=0u, kt1=(uint32_t)t; tf_block(kl0,kl1,kt0,kt1);   // fold_in(kloop, t)
    uint32_t q0, q1, v0, v1;
#if RNG_PART
    uint32_t p0=0u,p1=0u; tf_block(kt0,kt1,p0,p1);    // kp = split(kt)[0]
    uint32_t u0=0u,u1=1u; tf_block(kt0,kt1,u0,u1);    // ku = split(kt)[1]
    { uint32_t a=0u,b=1u; tf_block(p0,p1,a,b); q0=a; q1=b; }   // split(kp)[1]
    { uint32_t a=0u,b=1u; tf_block(u0,u1,a,b); v0=a; v1=b; }   // fold_in(ku,1)
#else
    uint32_t d00=0u,d01=2u; tf_block(kt0,kt1,d00,d01);
    uint32_t d10=1u,d11=3u; tf_block(kt0,kt1,d10,d11);
    uint32_t kp0=d00, kp1=d10, ku0=d01, ku1k=d11;
    uint32_t e00=0u,e01=2u; tf_block(kp0,kp1,e00,e01);
    uint32_t e10=1u,e11=3u; tf_block(kp0,kp1,e10,e11);
    q0=e01; q1=e11;
    { uint32_t a=0u,b=1u; tf_block(ku0,ku1k,a,b); v0=a; v1=b; }
#endif
    // T = T_INIT * exp(log_ratio * frac), all f32 boundaries, exp via f64 libm
    float fr = (float)t / 99.0f;
    float arg = log_ratio * fr;
    float T = (float)exp((double)arg);
    wsu[t*5+0]=q0; wsu[t*5+1]=q1; wsu[t*5+2]=v0; wsu[t*5+3]=v1;
    wsu[t*5+4]=__float_as_uint(T);
  }
}

// ---------------- KE: fused energies pipeline ----------------
// enc = f32(tanh(x@We + be))            [f64 acc, f64 tanh, f32 store]
// t2  = f32(enc @ W1e)                  [f64 acc]
// h   = tanh(tanh(t2 + W1i + b1))       [DOUBLE tanh — the reference's nested tanh]
// energies = 3 * tanh(sum_q h*w2 + b2); logits = -softplus(inv_temp)*energies
__global__ __launch_bounds__(256) void ke_kernel(
    const float* __restrict__ x, const float* __restrict__ We,
    const float* __restrict__ be, const float* __restrict__ W1,
    const float* __restrict__ b1, const float* __restrict__ w2,
    const float* __restrict__ b2, const float* __restrict__ invt,
    float* __restrict__ energ, float* __restrict__ logit){
#pragma clang fp contract(off)
  __shared__ float xs[32*16];
  __shared__ float enc_s[32*257];
  __shared__ float t2_s[32*4];
  const int tid = threadIdx.x;
  const int row0 = blockIdx.x * 32;
  const int rg = tid >> 6;           // 4 row-groups of 8 rows
  const int c0 = (tid & 63) * 4;     // 4 consecutive H-columns per thread
  double acc[8][4];
  #pragma unroll
  for (int r=0;r<8;++r){ acc[r][0]=0.0; acc[r][1]=0.0; acc[r][2]=0.0; acc[r][3]=0.0; }

  for (int v0=0; v0<V_N; v0+=16){
    #pragma unroll
    for (int k=0;k<2;++k){
      int e = tid + k*256;
      int r = e >> 4, c = e & 15;
      xs[r*16+c] = x[(size_t)(row0+r)*V_N + v0 + c];
    }
    __syncthreads();
    for (int vv=0; vv<16; ++vv){
      float4 wv = *(const float4*)(We + (size_t)(v0+vv)*H_N + c0);
      double w0=(double)wv.x, w1=(double)wv.y, w2d=(double)wv.z, w3=(double)wv.w;
      #pragma unroll
      for (int r8=0;r8<8;++r8){
        double xv = (double)xs[(rg*8+r8)*16 + vv];
        acc[r8][0] = fma(xv, w0, acc[r8][0]);
        acc[r8][1] = fma(xv, w1, acc[r8][1]);
        acc[r8][2] = fma(xv, w2d, acc[r8][2]);
        acc[r8][3] = fma(xv, w3, acc[r8][3]);
      }
    }
    __syncthreads();
  }
  #pragma unroll
  for (int r8=0;r8<8;++r8){
    int r = rg*8 + r8;
    #pragma unroll
    for (int j=0;j<4;++j){
      int c = c0 + j;
      float m1 = (float)(acc[r8][j] + (double)be[c]);   // f32 array boundary
      enc_s[r*257 + c] = (float)tanh((double)m1);        // libm tanh, f32 store
    }
  }
  __syncthreads();
  if (tid < 128){
    int r = tid >> 2, q = tid & 3;
    double s = 0.0;
    for (int h=0; h<H_N; ++h)
      s = fma((double)enc_s[r*257+h], (double)W1[h*4+q], s);
    t2_s[r*4+q] = (float)s;                              // f32 array boundary
  }
  __syncthreads();
  float nbeta = -(float)log1p(exp((double)invt[0]));     // -softplus(inv_temp)
  for (int p=0;p<2;++p){
    int id = tid + p*256;
    int r = id >> 4, e = id & 15;
    float y = 0.0f;
    #pragma unroll
    for (int q=0;q<4;++q){
      float a1 = t2_s[r*4+q] + W1[(H_N+e)*4+q];
      float a2 = a1 + b1[q];
      float hin  = (float)tanh((double)a2);              // inner tanh
      float hout = (float)tanh((double)hin);             // OUTER tanh (the fix)
      y = y + hout * w2[q];                              // unfused sequential reduce
    }
    float yb = y + b2[0];
    float en = 3.0f * (float)tanh((double)yb);
    size_t gi = (size_t)(row0 + r)*E_N + e;
    energ[gi] = en;
    logit[gi] = nbeta * en;
  }
}

// ---------------- SAMP: annealed Metropolis chain + one-hot write ----------------
__global__ __launch_bounds__(256) void samp_kernel(
    const float* __restrict__ energ, const unsigned* __restrict__ wsu,
    float* __restrict__ probs){
#pragma clang fp contract(off)
  __shared__ float se[256*16];
  const int lt = threadIdx.x;
  const int b = blockIdx.x*256 + lt;

  // KAT diagnostic channel (r2: passed; keep as regression guard)
  unsigned flag = wsu[502];
  if (flag != 0u){
    float c = 0.10f + 0.05f * (float)flag;
    float* op = probs + (size_t)b*E_N;
    #pragma unroll
    for (int j0=0; j0<16; j0+=4){
      float4 r; r.x=c; r.y=c; r.z=c; r.w=c;
      *(float4*)(op + j0) = r;
    }
    return;
  }

  float4* sv = (float4*)(se + lt*16);
  const float4* er = (const float4*)(energ + (size_t)b*E_N);
  sv[0]=er[0]; sv[1]=er[1]; sv[2]=er[2]; sv[3]=er[3];

  uint32_t k20 = wsu[500], k21 = wsu[501];
  uint32_t cur = rbits(k20, k21, (uint32_t)b) & 15u;

  for (int t=0; t<100; ++t){
    uint32_t pa=wsu[t*5+0], pb=wsu[t*5+1], ua=wsu[t*5+2], ub=wsu[t*5+3];
    float T = __uint_as_float(wsu[t*5+4]);
    uint32_t prop = rbits(pa, pb, (uint32_t)b) & 15u;
    uint32_t ru   = rbits(ua, ub, (uint32_t)b);
    float u = __uint_as_float((ru >> 9) | 0x3f800000u) - 1.0f;
    float ec = se[lt*16 + (int)cur];
    float ep = se[lt*16 + (int)prop];
    float d = ep - ec;
    float z = (-d) / T;
    z = fminf(z, 0.0f);
    float a = (float)exp((double)z);     // correctly-rounded f32 exp (libm-matching)
    cur = (u < a) ? prop : cur;
  }
  float* op = probs + (size_t)b*E_N;
  #pragma unroll
  for (int j0=0; j0<16; j0+=4){
    float4 r;
    r.x = (cur == (uint32_t)(j0+0)) ? 1.0f : 0.0f;
    r.y = (cur == (uint32_t)(j0+1)) ? 1.0f : 0.0f;
    r.z = (cur == (uint32_t)(j0+2)) ? 1.0f : 0.0f;
    r.w = (cur == (uint32_t)(j0+3)) ? 1.0f : 0.0f;
    *(float4*)(op + j0) = r;
  }
}

extern "C" void kernel_launch(void* const* d_in, const int* in_sizes, int n_in,
                              void* d_out, int out_size, void* d_ws, size_t ws_size,
                              hipStream_t stream) {
  const float* x   = (const float*)d_in[0];
  const float* We  = (const float*)d_in[1];
  const float* be  = (const float*)d_in[2];
  const float* W1  = (const float*)d_in[3];
  const float* b1  = (const float*)d_in[4];
  const float* w2  = (const float*)d_in[5];
  const float* b2  = (const float*)d_in[6];
  const float* itp = (const float*)d_in[7];
  float* out = (float*)d_out;
  float* probs = out;
  float* energ = out + (size_t)B_N*E_N;
  float* logit = out + 2*(size_t)B_N*E_N;
  unsigned* wsu = (unsigned*)d_ws;

  // log_ratio = f32(log(f64(f32(0.1)))) — log of the f32-rounded 0.1, correctly rounded
  float log_ratio = (float)log((double)((float)0.1));

  hipLaunchKernelGGL(s0_kernel, dim3(1), dim3(128), 0, stream, wsu, log_ratio);
  hipLaunchKernelGGL(ke_kernel, dim3(B_N/32), dim3(256), 0, stream,
                     x, We, be, W1, b1, w2, b2, itp, energ, logit);
  hipLaunchKernelGGL(samp_kernel, dim3(B_N/256), dim3(256), 0, stream,
                     energ, wsu, probs);
}